// Round 4
// baseline (255.379 us; speedup 1.0000x reference)
//
#include <hip/hip_runtime.h>
#include <hip/hip_bf16.h>

#define EDIM 256
#define INV_SQRT_D 0.17677669529663688f   // 1/sqrt(32)
#define NREP 8                            // accumulator replicas
#define GRID_MAIN 512                     // <= resident capacity (4/CU * 256 = 1024): barrier-safe

// ws layout:
//   float idx [4096..4103]  qb[h] = (q_h . bk_h)/sqrt(D)
//   float idx [4104..4111]  ub[h] = u_h . bv_h
//   float idx [4112]        c = w_lin . b_out + b_lin
//   u32   idx [4120]        grid-barrier arrival counter (zeroed by prep)
//   byte 36864..45055       Wb bf16[16][256]: rows 0..7 = (q_h^T Wk_h)/sqrt(D), 8..15 = u_h^T Wv_h
//   byte 65536..            zmf[NREP][G][16] f32: slot 2h = Z, 2h+1 = M
#define WS_QB   4096
#define WS_UB   4104
#define WS_C    4112
#define WS_FLAG 4120
#define WB_BYTE_OFF 36864
#define ZM_BYTE_OFF 65536

typedef __attribute__((ext_vector_type(8))) short short8;
typedef __attribute__((ext_vector_type(4))) float f32x4;

__device__ __forceinline__ unsigned short f2bf(float f) {
  unsigned u = __float_as_uint(f);
  unsigned r = (u + 0x7fffu + ((u >> 16) & 1u)) >> 16;   // RNE truncate to bf16
  return (unsigned short)r;
}

__device__ __forceinline__ unsigned int cvt_pk_bf16(float a, float b) {
  __hip_bfloat162 t = __float22bfloat162_rn(float2{a, b});  // v_cvt_pk_bf16_f32
  unsigned int u;
  __builtin_memcpy(&u, &t, 4);
  return u;
}

__device__ __forceinline__ double shfl_xor_dbl(double v, int m) {
  union { double d; int i[2]; } u;
  u.d = v;
  u.i[0] = __shfl_xor(u.i[0], m, 64);
  u.i[1] = __shfl_xor(u.i[1], m, 64);
  return u.d;
}

// ---------------- prep (single kernel, 33 blocks) ---------------------------
// b 0..7  : head-b score fold -> wb row b, qb[b]
// b 8..15 : value fold j=b-8  -> wb row 8+j, ub[j]
// b 16    : c scalar + zero barrier flag
// b 17..32: zero zmf
__global__ __launch_bounds__(256) void prep(
    const float* __restrict__ query, const float* __restrict__ w_in,
    const float* __restrict__ b_in, const float* __restrict__ w_out,
    const float* __restrict__ b_out, const float* __restrict__ b_lin,
    const float* __restrict__ w_lin, float* __restrict__ ws,
    unsigned short* __restrict__ wb, unsigned long long* __restrict__ zm,
    unsigned* __restrict__ flag, int nzm) {          // nzm in u64 units
  const int b = blockIdx.x, t = threadIdx.x;
  if (b < 8) {
    __shared__ float qh[32];
    {
      const int rl = t >> 3, sub = t & 7;
      const float4* wr = (const float4*)(w_in + (size_t)(b * 32 + rl) * EDIM + sub * 32);
      const float4* qr = (const float4*)(query + sub * 32);
      float p = 0.f;
#pragma unroll
      for (int f4 = 0; f4 < 8; ++f4) {
        const float4 w = wr[f4], q = qr[f4];
        p += w.x * q.x + w.y * q.y + w.z * q.z + w.w * q.w;
      }
      p += __shfl_xor(p, 1, 64);
      p += __shfl_xor(p, 2, 64);
      p += __shfl_xor(p, 4, 64);
      if (sub == 0) qh[rl] = p + b_in[b * 32 + rl];
    }
    __syncthreads();
    float a = 0.f;
#pragma unroll 8
    for (int d = 0; d < 32; ++d)
      a += qh[d] * w_in[(size_t)(EDIM + b * 32 + d) * EDIM + t];
    wb[b * EDIM + t] = f2bf(a * INV_SQRT_D);
    if (t < 64) {
      float s = (t < 32) ? qh[t] * b_in[EDIM + b * 32 + t] : 0.f;
#pragma unroll
      for (int m = 32; m >= 1; m >>= 1) s += __shfl_xor(s, m, 64);
      if (t == 0) ws[WS_QB + b] = s * INV_SQRT_D;
    }
  } else if (b < 16) {
    const int j = b - 8;
    __shared__ float uh[32];
    {
      const int dl = t >> 3, sub = t & 7;
      float p = 0.f;
#pragma unroll 8
      for (int f = sub * 32; f < sub * 32 + 32; ++f)
        p += w_lin[f] * w_out[(size_t)f * EDIM + j * 32 + dl];
      p += __shfl_xor(p, 1, 64);
      p += __shfl_xor(p, 2, 64);
      p += __shfl_xor(p, 4, 64);
      if (sub == 0) uh[dl] = p;
    }
    __syncthreads();
    float a = 0.f;
#pragma unroll 8
    for (int d = 0; d < 32; ++d)
      a += uh[d] * w_in[(size_t)(2 * EDIM + j * 32 + d) * EDIM + t];
    wb[(8 + j) * EDIM + t] = f2bf(a);
    if (t < 64) {
      float s = (t < 32) ? uh[t] * b_in[2 * EDIM + j * 32 + t] : 0.f;
#pragma unroll
      for (int m = 32; m >= 1; m >>= 1) s += __shfl_xor(s, m, 64);
      if (t == 0) ws[WS_UB + j] = s;
    }
  } else if (b == 16) {
    __shared__ float red[256];
    red[t] = w_lin[t] * b_out[t];
    __syncthreads();
    for (int off = 128; off >= 1; off >>= 1) {
      if (t < off) red[t] += red[t + off];
      __syncthreads();
    }
    if (t == 0) ws[WS_C] = red[0] + b_lin[0];
    if (t == 1) *flag = 0u;          // barrier counter init (pre-main, same stream)
  } else {
    for (int k = (b - 17) * 256 + t; k < nzm; k += 16 * 256) zm[k] = 0ull;
  }
}

// ---------------- main: MFMA stream + fused finalize (grid barrier) ---------
// A-fragment layout for mfma_f32_16x16x32_bf16: lane (n = lane&15, quad =
// lane>>4) holds A[m=n][k=quad*8+j], j=0..7. We load exactly that from x:
// item base+n, feats quad*8 + kc*32 .. +8 (32 B/lane; the wave covers
// 16 items x 128 B contiguous per kc step -> full line utilization).
// Epilogue: f32 atomics into one of NREP replicas (blockIdx&7).
// After all tiles: device-scope arrival counter; all 512 blocks co-resident
// (capacity 1024 at 4 blocks/CU via launch bounds) so the spin cannot
// deadlock; then each block finalizes its own G/grid groups (agent-scope
// loads bypass stale L1) and writes out directly. Removes the finalize launch.
__global__ __launch_bounds__(256, 4) void main_mfma(
    const float* __restrict__ x, const int* __restrict__ gid,
    const float* __restrict__ ws, const unsigned short* __restrict__ wb,
    float* __restrict__ zmf, float* __restrict__ out,
    unsigned* __restrict__ flag, int g16, int n_items, int G) {
  const int t = threadIdx.x;
  const int lane = t & 63;
  const int n = lane & 15, quad = lane >> 4;
  const int h = n & 7, isw = (n >> 3) & 1;   // n<8: Z (score) slot, n>=8: M slot

  // B fragments: Wb row n (slot), feats quad*8 + kc*32 .. +8
  short8 bfrag[8];
#pragma unroll
  for (int kc = 0; kc < 8; ++kc)
    bfrag[kc] = *(const short8*)(wb + n * EDIM + quad * 8 + kc * 32);

  const float qb = ws[WS_QB + h];
  const float ub = ws[WS_UB + h];
  const float c = ws[WS_C];

  float* __restrict__ zr = zmf + (size_t)(blockIdx.x & (NREP - 1)) * g16;

  const int wid = (int)(blockIdx.x * (blockDim.x >> 6) + (t >> 6));
  const int nw = (int)(gridDim.x * (blockDim.x >> 6));
  const int ntiles = (n_items + 15) >> 4;

  for (int tile = wid; tile < ntiles; tile += nw) {
    const int base = tile << 4;
    const float* rowp = x + (size_t)(base + n) * EDIM + quad * 8;
    f32x4 acc = {0.f, 0.f, 0.f, 0.f};
    int4 g4;
    if (base + 16 <= n_items) {                    // full tile (hot path)
      g4 = *(const int4*)(gid + base + quad * 4);
#pragma unroll
      for (int kc = 0; kc < 8; ++kc) {
        const float4 v0 = *(const float4*)(rowp + kc * 32);
        const float4 v1 = *(const float4*)(rowp + kc * 32 + 4);
        union { short8 s; unsigned int u[4]; } a;
        a.u[0] = cvt_pk_bf16(v0.x, v0.y);
        a.u[1] = cvt_pk_bf16(v0.z, v0.w);
        a.u[2] = cvt_pk_bf16(v1.x, v1.y);
        a.u[3] = cvt_pk_bf16(v1.z, v1.w);
        acc = __builtin_amdgcn_mfma_f32_16x16x32_bf16(a.s, bfrag[kc], acc, 0, 0, 0);
      }
    } else {                                       // tail tile (unused at N=131072)
      int gg[4];
#pragma unroll
      for (int r = 0; r < 4; ++r)
        gg[r] = (base + quad * 4 + r < n_items) ? gid[base + quad * 4 + r] : 0;
      g4.x = gg[0]; g4.y = gg[1]; g4.z = gg[2]; g4.w = gg[3];
      const bool live = (base + n < n_items);
#pragma unroll
      for (int kc = 0; kc < 8; ++kc) {
        float4 v0 = {0.f, 0.f, 0.f, 0.f}, v1 = {0.f, 0.f, 0.f, 0.f};
        if (live) {
          v0 = *(const float4*)(rowp + kc * 32);
          v1 = *(const float4*)(rowp + kc * 32 + 4);
        }
        union { short8 s; unsigned int u[4]; } a;
        a.u[0] = cvt_pk_bf16(v0.x, v0.y);
        a.u[1] = cvt_pk_bf16(v0.z, v0.w);
        a.u[2] = cvt_pk_bf16(v1.x, v1.y);
        a.u[3] = cvt_pk_bf16(v1.z, v1.w);
        acc = __builtin_amdgcn_mfma_f32_16x16x32_bf16(a.s, bfrag[kc], acc, 0, 0, 0);
      }
    }
    // epilogue: C[m][n] with m = quad*4 + r (item), n = slot
#pragma unroll
    for (int r = 0; r < 4; ++r) {
      const float mine = acc[r];
      const float partner = __shfl_xor(mine, 8, 64);   // slot n^8, same item
      const float sv = (isw ? partner : mine) + qb;
      const float wv = (isw ? mine : partner) + ub;
      const float e = __expf(sv);
      const float val = isw ? e * wv : e;
      const int g = (r == 0) ? g4.x : (r == 1) ? g4.y : (r == 2) ? g4.z : g4.w;
      if (base + quad * 4 + r < n_items)
        atomicAdd(zr + ((size_t)g * 16 + h * 2 + isw), val);
    }
  }

  // ---- grid-wide arrival barrier (all blocks co-resident by construction) --
  __syncthreads();
  if (t == 0) {
    __threadfence();                                   // drain my zmf atomics
    __hip_atomic_fetch_add(flag, 1u, __ATOMIC_ACQ_REL, __HIP_MEMORY_SCOPE_AGENT);
    while (__hip_atomic_load(flag, __ATOMIC_ACQUIRE, __HIP_MEMORY_SCOPE_AGENT)
           < (unsigned)gridDim.x)
      __builtin_amdgcn_s_sleep(1);
  }
  __syncthreads();

  // ---- fused finalize: this block's gpb groups, one wave per group ---------
  const int gpb = (G + (int)gridDim.x - 1) / (int)gridDim.x;   // 4 at G=2048
  const int gl = t >> 6;                                       // wave id 0..3
  const int g = (int)blockIdx.x * gpb + gl;
  if (gl < gpb && g < G) {
    const int slot = lane & 15;
    const int rp = lane >> 4;                                  // 0..3
    float v = 0.f;
#pragma unroll
    for (int rep = rp; rep < NREP; rep += 4)
      v += __hip_atomic_load(zmf + (size_t)rep * g16 + (size_t)g * 16 + slot,
                             __ATOMIC_RELAXED, __HIP_MEMORY_SCOPE_AGENT);
    v += __shfl_xor(v, 16, 64);
    v += __shfl_xor(v, 32, 64);          // lanes 0..15: full sum for their slot
    const float partner = __shfl_xor(v, 1, 64);
    double dr = 0.0;
    if (lane < 16 && !(slot & 1))
      dr = (double)partner / (double)v;  // even slot: Z here, M in partner
    dr += shfl_xor_dbl(dr, 2);
    dr += shfl_xor_dbl(dr, 4);
    dr += shfl_xor_dbl(dr, 8);
    if (lane == 0) out[g] = (float)((double)c + dr);
  }
}

// ---------------- Plan B (ws too small): one block per group, no scratch ----
__device__ __forceinline__ float dot16_reduce(const float4 (&W)[16],
                                              const float4 xv, const int lane) {
  float p[16];
#pragma unroll
  for (int j = 0; j < 16; ++j)
    p[j] = W[j].x * xv.x + W[j].y * xv.y + W[j].z * xv.z + W[j].w * xv.w;
#pragma unroll
  for (int j = 0; j < 8; ++j) {
    float send = (lane & 1) ? p[j] : p[j + 8];
    float keep = (lane & 1) ? p[j + 8] : p[j];
    p[j] = keep + __shfl_xor(send, 1, 64);
  }
#pragma unroll
  for (int j = 0; j < 4; ++j) {
    float send = (lane & 2) ? p[j] : p[j + 4];
    float keep = (lane & 2) ? p[j + 4] : p[j];
    p[j] = keep + __shfl_xor(send, 2, 64);
  }
#pragma unroll
  for (int j = 0; j < 2; ++j) {
    float send = (lane & 4) ? p[j] : p[j + 2];
    float keep = (lane & 4) ? p[j + 2] : p[j];
    p[j] = keep + __shfl_xor(send, 4, 64);
  }
  {
    float send = (lane & 8) ? p[0] : p[1];
    float keep = (lane & 8) ? p[1] : p[0];
    p[0] = keep + __shfl_xor(send, 8, 64);
  }
  p[0] += __shfl_xor(p[0], 16, 64);
  p[0] += __shfl_xor(p[0], 32, 64);
  return p[0];
}

__device__ __forceinline__ int bitrev4(const int l4) {
  return ((l4 & 1) << 3) | ((l4 & 2) << 1) | ((l4 & 4) >> 1) | ((l4 & 8) >> 3);
}

__global__ __launch_bounds__(256) void group_scan(
    const float* __restrict__ x, const int* __restrict__ gid,
    const float* __restrict__ query, const float* __restrict__ w_in,
    const float* __restrict__ b_in, const float* __restrict__ w_out,
    const float* __restrict__ b_out, const float* __restrict__ w_lin,
    const float* __restrict__ b_lin, float* __restrict__ out, int n_items) {
  const int g = blockIdx.x;
  const int t = threadIdx.x;
  __shared__ float Wl[16 * EDIM];
  __shared__ float querys[EDIM], wls[EDIM], qs[EDIM], us[EDIM];
  __shared__ float qbias[8], ubias[8], csh;
  __shared__ float part[4][16], sums[16];

  querys[t] = query[t];
  wls[t] = w_lin[t];
  __syncthreads();
  {
    float acc = 0.f;
    const float4* wr = (const float4*)(w_in + (size_t)t * EDIM);
    for (int f4 = 0; f4 < EDIM / 4; ++f4) {
      float4 wv = wr[f4];
      int f = f4 * 4;
      acc += wv.x * querys[f] + wv.y * querys[f + 1] + wv.z * querys[f + 2] + wv.w * querys[f + 3];
    }
    qs[t] = acc + b_in[t];
  }
  {
    float acc = 0.f;
    for (int f = 0; f < EDIM; ++f) acc += wls[f] * w_out[(size_t)f * EDIM + t];
    us[t] = acc;
  }
  __syncthreads();
  for (int j = 0; j < 8; ++j) {
    float a = 0.f;
    for (int d = 0; d < 32; ++d)
      a += qs[j * 32 + d] * w_in[(size_t)(EDIM + j * 32 + d) * EDIM + t];
    Wl[j * EDIM + t] = a * INV_SQRT_D;
  }
  for (int j = 0; j < 8; ++j) {
    float a = 0.f;
    for (int d = 0; d < 32; ++d)
      a += us[j * 32 + d] * w_in[(size_t)(2 * EDIM + j * 32 + d) * EDIM + t];
    Wl[(8 + j) * EDIM + t] = a;
  }
  if (t < 8) {
    float qb = 0.f, ub = 0.f;
    for (int d = 0; d < 32; ++d) {
      qb += qs[t * 32 + d] * b_in[EDIM + t * 32 + d];
      ub += us[t * 32 + d] * b_in[2 * EDIM + t * 32 + d];
    }
    qbias[t] = qb * INV_SQRT_D;
    ubias[t] = ub;
  }
  if (t == 0) {
    float c = b_lin[0];
    for (int f = 0; f < EDIM; ++f) c += wls[f] * b_out[f];
    csh = c;
  }
  __syncthreads();

  const int lane = t & 63;
  const int wave = t >> 6;
  float4 W[16];
#pragma unroll
  for (int j = 0; j < 16; ++j)
    W[j] = *(const float4*)(Wl + j * EDIM + lane * 4);
  const int jv = bitrev4(lane & 15);
  const int h = jv & 7;
  const int isw = (jv >> 3) & 1;
  const float bias_s = qbias[h];
  const float bias_w = ubias[h];

  float accv = 0.f;
  const int nchunk = (n_items + 63) >> 6;
  for (int c = wave; c < nchunk; c += 4) {
    const int i0 = c << 6;
    const int ii = i0 + lane;
    const int gi = (ii < n_items) ? gid[ii] : -1;
    unsigned long long mk = __ballot(gi == g);
    while (mk) {
      const int bpos = __ffsll(mk) - 1;
      mk &= mk - 1;
      const int i = i0 + bpos;
      const float4 xv = *(const float4*)(x + (size_t)i * EDIM + lane * 4);
      const float p0 = dot16_reduce(W, xv, lane);
      const float tpair = __shfl_xor(p0, 1, 64);
      const float sv = (isw ? tpair : p0) + bias_s;
      const float wv = (isw ? p0 : tpair) + bias_w;
      const float e = __expf(sv);
      accv += isw ? e * wv : e;
    }
  }
  if (lane < 16) part[wave][h * 2 + isw] = accv;
  __syncthreads();
  if (t < 16) sums[t] = part[0][t] + part[1][t] + part[2][t] + part[3][t];
  __syncthreads();
  if (t == 0) {
    double acc = (double)csh;
    for (int hh = 0; hh < 8; ++hh)
      acc += (double)sums[2 * hh + 1] / (double)sums[2 * hh];
    out[g] = (float)acc;
  }
}

extern "C" void kernel_launch(void* const* d_in, const int* in_sizes, int n_in,
                              void* d_out, int out_size, void* d_ws, size_t ws_size,
                              hipStream_t stream) {
  const float* tree_preds = (const float*)d_in[0];
  const int* group_ids = (const int*)d_in[1];
  const float* query = (const float*)d_in[2];
  const float* w_in = (const float*)d_in[3];
  const float* b_in = (const float*)d_in[4];
  const float* w_out = (const float*)d_in[5];
  const float* b_out = (const float*)d_in[6];
  const float* w_lin = (const float*)d_in[7];
  const float* b_lin = (const float*)d_in[8];
  float* out = (float*)d_out;

  const int N = in_sizes[1];   // 131072
  const int G = out_size;      // 2048

  const size_t needA = (size_t)ZM_BYTE_OFF + (size_t)NREP * G * 16 * 4;
  if (ws_size >= needA) {
    float* ws = (float*)d_ws;
    unsigned short* wb = (unsigned short*)((char*)d_ws + WB_BYTE_OFF);
    float* zmf = (float*)((char*)d_ws + ZM_BYTE_OFF);
    unsigned* flag = (unsigned*)((char*)d_ws + WS_FLAG * 4);
    // zero count in u64 units: NREP*G*16 floats / 2
    prep<<<33, 256, 0, stream>>>(query, w_in, b_in, w_out, b_out, b_lin, w_lin,
                                 ws, wb, (unsigned long long*)zmf, flag,
                                 NREP * G * 8);
    main_mfma<<<GRID_MAIN, 256, 0, stream>>>(tree_preds, group_ids, ws, wb, zmf,
                                             out, flag, G * 16, N, G);
  } else {
    group_scan<<<G, 256, 0, stream>>>(tree_preds, group_ids, query, w_in, b_in,
                                      w_out, b_out, w_lin, b_lin, out, N);
  }
}

// Round 5
// 221.112 us; speedup vs baseline: 1.1550x; 1.1550x over previous
//
#include <hip/hip_runtime.h>
#include <hip/hip_bf16.h>

#define EDIM 256
#define INV_SQRT_D 0.17677669529663688f   // 1/sqrt(32)
#define NREP 8                            // accumulator replicas
#define GRID_MAIN 2048                    // 8 blocks/CU * 256 CU: full residency at bounds (256,8)

// ws layout:
//   float idx [4096..4103]  qb[h] = (q_h . bk_h)/sqrt(D)
//   float idx [4104..4111]  ub[h] = u_h . bv_h
//   float idx [4112]        c = w_lin . b_out + b_lin
//   byte 36864..45055       Wb bf16[16][256]: rows 0..7 = (q_h^T Wk_h)/sqrt(D), 8..15 = u_h^T Wv_h
//   byte 65536..            zmf[NREP][G][16] f32: slot 2h = Z, 2h+1 = M
#define WS_QB   4096
#define WS_UB   4104
#define WS_C    4112
#define WB_BYTE_OFF 36864
#define ZM_BYTE_OFF 65536

typedef __attribute__((ext_vector_type(8))) short short8;
typedef __attribute__((ext_vector_type(4))) float f32x4;

__device__ __forceinline__ unsigned short f2bf(float f) {
  unsigned u = __float_as_uint(f);
  unsigned r = (u + 0x7fffu + ((u >> 16) & 1u)) >> 16;   // RNE truncate to bf16
  return (unsigned short)r;
}

__device__ __forceinline__ unsigned int cvt_pk_bf16(float a, float b) {
  __hip_bfloat162 t = __float22bfloat162_rn(float2{a, b});  // v_cvt_pk_bf16_f32
  unsigned int u;
  __builtin_memcpy(&u, &t, 4);
  return u;
}

// ---------------- prep (single kernel, 33 blocks) ---------------------------
// b 0..7  : head-b score fold -> wb row b, qb[b]
// b 8..15 : value fold j=b-8  -> wb row 8+j, ub[j]
// b 16    : c scalar
// b 17..32: zero zmf
__global__ __launch_bounds__(256) void prep(
    const float* __restrict__ query, const float* __restrict__ w_in,
    const float* __restrict__ b_in, const float* __restrict__ w_out,
    const float* __restrict__ b_out, const float* __restrict__ b_lin,
    const float* __restrict__ w_lin, float* __restrict__ ws,
    unsigned short* __restrict__ wb, unsigned long long* __restrict__ zm,
    int nzm) {                                       // nzm in u64 units
  const int b = blockIdx.x, t = threadIdx.x;
  if (b < 8) {
    __shared__ float qh[32];
    {
      const int rl = t >> 3, sub = t & 7;
      const float4* wr = (const float4*)(w_in + (size_t)(b * 32 + rl) * EDIM + sub * 32);
      const float4* qr = (const float4*)(query + sub * 32);
      float p = 0.f;
#pragma unroll
      for (int f4 = 0; f4 < 8; ++f4) {
        const float4 w = wr[f4], q = qr[f4];
        p += w.x * q.x + w.y * q.y + w.z * q.z + w.w * q.w;
      }
      p += __shfl_xor(p, 1, 64);
      p += __shfl_xor(p, 2, 64);
      p += __shfl_xor(p, 4, 64);
      if (sub == 0) qh[rl] = p + b_in[b * 32 + rl];
    }
    __syncthreads();
    float a = 0.f;
#pragma unroll 8
    for (int d = 0; d < 32; ++d)
      a += qh[d] * w_in[(size_t)(EDIM + b * 32 + d) * EDIM + t];
    wb[b * EDIM + t] = f2bf(a * INV_SQRT_D);
    if (t < 64) {
      float s = (t < 32) ? qh[t] * b_in[EDIM + b * 32 + t] : 0.f;
#pragma unroll
      for (int m = 32; m >= 1; m >>= 1) s += __shfl_xor(s, m, 64);
      if (t == 0) ws[WS_QB + b] = s * INV_SQRT_D;
    }
  } else if (b < 16) {
    const int j = b - 8;
    __shared__ float uh[32];
    {
      const int dl = t >> 3, sub = t & 7;
      float p = 0.f;
#pragma unroll 8
      for (int f = sub * 32; f < sub * 32 + 32; ++f)
        p += w_lin[f] * w_out[(size_t)f * EDIM + j * 32 + dl];
      p += __shfl_xor(p, 1, 64);
      p += __shfl_xor(p, 2, 64);
      p += __shfl_xor(p, 4, 64);
      if (sub == 0) uh[dl] = p;
    }
    __syncthreads();
    float a = 0.f;
#pragma unroll 8
    for (int d = 0; d < 32; ++d)
      a += uh[d] * w_in[(size_t)(2 * EDIM + j * 32 + d) * EDIM + t];
    wb[(8 + j) * EDIM + t] = f2bf(a);
    if (t < 64) {
      float s = (t < 32) ? uh[t] * b_in[2 * EDIM + j * 32 + t] : 0.f;
#pragma unroll
      for (int m = 32; m >= 1; m >>= 1) s += __shfl_xor(s, m, 64);
      if (t == 0) ws[WS_UB + j] = s;
    }
  } else if (b == 16) {
    __shared__ float red[256];
    red[t] = w_lin[t] * b_out[t];
    __syncthreads();
    for (int off = 128; off >= 1; off >>= 1) {
      if (t < off) red[t] += red[t + off];
      __syncthreads();
    }
    if (t == 0) ws[WS_C] = red[0] + b_lin[0];
  } else {
    for (int k = (b - 17) * 256 + t; k < nzm; k += 16 * 256) zm[k] = 0ull;
  }
}

// ---------------- main: direct-fragment MFMA per 16-item tile, no LDS -------
// A-fragment layout for mfma_f32_16x16x32_bf16: lane (n = lane&15, quad =
// lane>>4) holds A[m=n][k=quad*8+j], j=0..7. We load exactly that from x:
// item base+n, feats quad*8 + kc*32 .. +8 (32 B/lane; the wave covers
// 16 items x 128 B contiguous per kc step -> full line utilization).
// Latency-bound kernel (R4 counters: VALUBusy 2.3%, 692 GB/s at 8 waves/CU):
// run at MAX occupancy -> __launch_bounds__(256,8) = 8 waves/SIMD, grid 2048
// = 8 blocks/CU fully resident, 1 tile per wave. VGPR=52 fits the 64 budget.
__global__ __launch_bounds__(256, 8) void main_mfma(
    const float* __restrict__ x, const int* __restrict__ gid,
    const float* __restrict__ ws, const unsigned short* __restrict__ wb,
    float* __restrict__ zmf, int g16, int n_items) {
  const int t = threadIdx.x;
  const int lane = t & 63;
  const int n = lane & 15, quad = lane >> 4;
  const int h = n & 7, isw = (n >> 3) & 1;   // n<8: Z (score) slot, n>=8: M slot

  // B fragments: Wb row n (slot), feats quad*8 + kc*32 .. +8
  short8 bfrag[8];
#pragma unroll
  for (int kc = 0; kc < 8; ++kc)
    bfrag[kc] = *(const short8*)(wb + n * EDIM + quad * 8 + kc * 32);

  const float qb = ws[WS_QB + h];
  const float ub = ws[WS_UB + h];

  float* __restrict__ zr = zmf + (size_t)(blockIdx.x & (NREP - 1)) * g16;

  const int wid = (int)(blockIdx.x * (blockDim.x >> 6) + (t >> 6));
  const int nw = (int)(gridDim.x * (blockDim.x >> 6));
  const int ntiles = (n_items + 15) >> 4;

  for (int tile = wid; tile < ntiles; tile += nw) {
    const int base = tile << 4;
    const float* rowp = x + (size_t)(base + n) * EDIM + quad * 8;
    f32x4 acc = {0.f, 0.f, 0.f, 0.f};
    int4 g4;
    if (base + 16 <= n_items) {                    // full tile (hot path)
      g4 = *(const int4*)(gid + base + quad * 4);
#pragma unroll
      for (int kc = 0; kc < 8; ++kc) {
        const float4 v0 = *(const float4*)(rowp + kc * 32);
        const float4 v1 = *(const float4*)(rowp + kc * 32 + 4);
        union { short8 s; unsigned int u[4]; } a;
        a.u[0] = cvt_pk_bf16(v0.x, v0.y);
        a.u[1] = cvt_pk_bf16(v0.z, v0.w);
        a.u[2] = cvt_pk_bf16(v1.x, v1.y);
        a.u[3] = cvt_pk_bf16(v1.z, v1.w);
        acc = __builtin_amdgcn_mfma_f32_16x16x32_bf16(a.s, bfrag[kc], acc, 0, 0, 0);
      }
    } else {                                       // tail tile (unused at N=131072)
      int gg[4];
#pragma unroll
      for (int r = 0; r < 4; ++r)
        gg[r] = (base + quad * 4 + r < n_items) ? gid[base + quad * 4 + r] : 0;
      g4.x = gg[0]; g4.y = gg[1]; g4.z = gg[2]; g4.w = gg[3];
      const bool live = (base + n < n_items);
#pragma unroll
      for (int kc = 0; kc < 8; ++kc) {
        float4 v0 = {0.f, 0.f, 0.f, 0.f}, v1 = {0.f, 0.f, 0.f, 0.f};
        if (live) {
          v0 = *(const float4*)(rowp + kc * 32);
          v1 = *(const float4*)(rowp + kc * 32 + 4);
        }
        union { short8 s; unsigned int u[4]; } a;
        a.u[0] = cvt_pk_bf16(v0.x, v0.y);
        a.u[1] = cvt_pk_bf16(v0.z, v0.w);
        a.u[2] = cvt_pk_bf16(v1.x, v1.y);
        a.u[3] = cvt_pk_bf16(v1.z, v1.w);
        acc = __builtin_amdgcn_mfma_f32_16x16x32_bf16(a.s, bfrag[kc], acc, 0, 0, 0);
      }
    }
    // epilogue: C[m][n] with m = quad*4 + r (item), n = slot
#pragma unroll
    for (int r = 0; r < 4; ++r) {
      const float mine = acc[r];
      const float partner = __shfl_xor(mine, 8, 64);   // slot n^8, same item
      const float sv = (isw ? partner : mine) + qb;
      const float wv = (isw ? mine : partner) + ub;
      const float e = __expf(sv);
      const float val = isw ? e * wv : e;
      const int g = (r == 0) ? g4.x : (r == 1) ? g4.y : (r == 2) ? g4.z : g4.w;
      if (base + quad * 4 + r < n_items)
        atomicAdd(zr + ((size_t)g * 16 + h * 2 + isw), val);
    }
  }
}

// ---------------- finalize: out[g] = c + sum_h M/Z over NREP replicas -------
__global__ __launch_bounds__(256) void finalize(
    const float* __restrict__ zmf, const float* __restrict__ ws,
    float* __restrict__ out, int G) {
  const int g = blockIdx.x * blockDim.x + threadIdx.x;
  if (g >= G) return;
  float zs[8], ms[8];
#pragma unroll
  for (int hh = 0; hh < 8; ++hh) { zs[hh] = 0.f; ms[hh] = 0.f; }
  const int g16 = G * 16;
#pragma unroll
  for (int rep = 0; rep < NREP; ++rep) {
    const float* row = zmf + (size_t)rep * g16 + (size_t)g * 16;
#pragma unroll
    for (int hh = 0; hh < 8; ++hh) {
      zs[hh] += row[hh * 2];
      ms[hh] += row[hh * 2 + 1];
    }
  }
  double acc = (double)ws[WS_C];
#pragma unroll
  for (int hh = 0; hh < 8; ++hh)
    acc += (double)ms[hh] / (double)zs[hh];
  out[g] = (float)acc;
}

// ---------------- Plan B (ws too small): one block per group, no scratch ----
__device__ __forceinline__ float dot16_reduce(const float4 (&W)[16],
                                              const float4 xv, const int lane) {
  float p[16];
#pragma unroll
  for (int j = 0; j < 16; ++j)
    p[j] = W[j].x * xv.x + W[j].y * xv.y + W[j].z * xv.z + W[j].w * xv.w;
#pragma unroll
  for (int j = 0; j < 8; ++j) {
    float send = (lane & 1) ? p[j] : p[j + 8];
    float keep = (lane & 1) ? p[j + 8] : p[j];
    p[j] = keep + __shfl_xor(send, 1, 64);
  }
#pragma unroll
  for (int j = 0; j < 4; ++j) {
    float send = (lane & 2) ? p[j] : p[j + 4];
    float keep = (lane & 2) ? p[j + 4] : p[j];
    p[j] = keep + __shfl_xor(send, 2, 64);
  }
#pragma unroll
  for (int j = 0; j < 2; ++j) {
    float send = (lane & 4) ? p[j] : p[j + 2];
    float keep = (lane & 4) ? p[j + 2] : p[j];
    p[j] = keep + __shfl_xor(send, 4, 64);
  }
  {
    float send = (lane & 8) ? p[0] : p[1];
    float keep = (lane & 8) ? p[1] : p[0];
    p[0] = keep + __shfl_xor(send, 8, 64);
  }
  p[0] += __shfl_xor(p[0], 16, 64);
  p[0] += __shfl_xor(p[0], 32, 64);
  return p[0];
}

__device__ __forceinline__ int bitrev4(const int l4) {
  return ((l4 & 1) << 3) | ((l4 & 2) << 1) | ((l4 & 4) >> 1) | ((l4 & 8) >> 3);
}

__global__ __launch_bounds__(256) void group_scan(
    const float* __restrict__ x, const int* __restrict__ gid,
    const float* __restrict__ query, const float* __restrict__ w_in,
    const float* __restrict__ b_in, const float* __restrict__ w_out,
    const float* __restrict__ b_out, const float* __restrict__ w_lin,
    const float* __restrict__ b_lin, float* __restrict__ out, int n_items) {
  const int g = blockIdx.x;
  const int t = threadIdx.x;
  __shared__ float Wl[16 * EDIM];
  __shared__ float querys[EDIM], wls[EDIM], qs[EDIM], us[EDIM];
  __shared__ float qbias[8], ubias[8], csh;
  __shared__ float part[4][16], sums[16];

  querys[t] = query[t];
  wls[t] = w_lin[t];
  __syncthreads();
  {
    float acc = 0.f;
    const float4* wr = (const float4*)(w_in + (size_t)t * EDIM);
    for (int f4 = 0; f4 < EDIM / 4; ++f4) {
      float4 wv = wr[f4];
      int f = f4 * 4;
      acc += wv.x * querys[f] + wv.y * querys[f + 1] + wv.z * querys[f + 2] + wv.w * querys[f + 3];
    }
    qs[t] = acc + b_in[t];
  }
  {
    float acc = 0.f;
    for (int f = 0; f < EDIM; ++f) acc += wls[f] * w_out[(size_t)f * EDIM + t];
    us[t] = acc;
  }
  __syncthreads();
  for (int j = 0; j < 8; ++j) {
    float a = 0.f;
    for (int d = 0; d < 32; ++d)
      a += qs[j * 32 + d] * w_in[(size_t)(EDIM + j * 32 + d) * EDIM + t];
    Wl[j * EDIM + t] = a * INV_SQRT_D;
  }
  for (int j = 0; j < 8; ++j) {
    float a = 0.f;
    for (int d = 0; d < 32; ++d)
      a += us[j * 32 + d] * w_in[(size_t)(2 * EDIM + j * 32 + d) * EDIM + t];
    Wl[(8 + j) * EDIM + t] = a;
  }
  if (t < 8) {
    float qb = 0.f, ub = 0.f;
    for (int d = 0; d < 32; ++d) {
      qb += qs[t * 32 + d] * b_in[EDIM + t * 32 + d];
      ub += us[t * 32 + d] * b_in[2 * EDIM + t * 32 + d];
    }
    qbias[t] = qb * INV_SQRT_D;
    ubias[t] = ub;
  }
  if (t == 0) {
    float c = b_lin[0];
    for (int f = 0; f < EDIM; ++f) c += wls[f] * b_out[f];
    csh = c;
  }
  __syncthreads();

  const int lane = t & 63;
  const int wave = t >> 6;
  float4 W[16];
#pragma unroll
  for (int j = 0; j < 16; ++j)
    W[j] = *(const float4*)(Wl + j * EDIM + lane * 4);
  const int jv = bitrev4(lane & 15);
  const int h = jv & 7;
  const int isw = (jv >> 3) & 1;
  const float bias_s = qbias[h];
  const float bias_w = ubias[h];

  float accv = 0.f;
  const int nchunk = (n_items + 63) >> 6;
  for (int c = wave; c < nchunk; c += 4) {
    const int i0 = c << 6;
    const int ii = i0 + lane;
    const int gi = (ii < n_items) ? gid[ii] : -1;
    unsigned long long mk = __ballot(gi == g);
    while (mk) {
      const int bpos = __ffsll(mk) - 1;
      mk &= mk - 1;
      const int i = i0 + bpos;
      const float4 xv = *(const float4*)(x + (size_t)i * EDIM + lane * 4);
      const float p0 = dot16_reduce(W, xv, lane);
      const float tpair = __shfl_xor(p0, 1, 64);
      const float sv = (isw ? tpair : p0) + bias_s;
      const float wv = (isw ? p0 : tpair) + bias_w;
      const float e = __expf(sv);
      accv += isw ? e * wv : e;
    }
  }
  if (lane < 16) part[wave][h * 2 + isw] = accv;
  __syncthreads();
  if (t < 16) sums[t] = part[0][t] + part[1][t] + part[2][t] + part[3][t];
  __syncthreads();
  if (t == 0) {
    double acc = (double)csh;
    for (int hh = 0; hh < 8; ++hh)
      acc += (double)sums[2 * hh + 1] / (double)sums[2 * hh];
    out[g] = (float)acc;
  }
}

extern "C" void kernel_launch(void* const* d_in, const int* in_sizes, int n_in,
                              void* d_out, int out_size, void* d_ws, size_t ws_size,
                              hipStream_t stream) {
  const float* tree_preds = (const float*)d_in[0];
  const int* group_ids = (const int*)d_in[1];
  const float* query = (const float*)d_in[2];
  const float* w_in = (const float*)d_in[3];
  const float* b_in = (const float*)d_in[4];
  const float* w_out = (const float*)d_in[5];
  const float* b_out = (const float*)d_in[6];
  const float* w_lin = (const float*)d_in[7];
  const float* b_lin = (const float*)d_in[8];
  float* out = (float*)d_out;

  const int N = in_sizes[1];   // 131072
  const int G = out_size;      // 2048

  const size_t needA = (size_t)ZM_BYTE_OFF + (size_t)NREP * G * 16 * 4;
  if (ws_size >= needA) {
    float* ws = (float*)d_ws;
    unsigned short* wb = (unsigned short*)((char*)d_ws + WB_BYTE_OFF);
    float* zmf = (float*)((char*)d_ws + ZM_BYTE_OFF);
    // zero count in u64 units: NREP*G*16 floats / 2
    prep<<<33, 256, 0, stream>>>(query, w_in, b_in, w_out, b_out, b_lin, w_lin,
                                 ws, wb, (unsigned long long*)zmf, NREP * G * 8);
    main_mfma<<<GRID_MAIN, 256, 0, stream>>>(tree_preds, group_ids, ws, wb, zmf,
                                             G * 16, N);
    finalize<<<(G + 255) / 256, 256, 0, stream>>>(zmf, ws, out, G);
  } else {
    group_scan<<<G, 256, 0, stream>>>(tree_preds, group_ids, query, w_in, b_in,
                                      w_out, b_out, w_lin, b_lin, out, N);
  }
}

// Round 6
// 216.874 us; speedup vs baseline: 1.1775x; 1.0195x over previous
//
#include <hip/hip_runtime.h>
#include <hip/hip_bf16.h>

#define EDIM 256
#define INV_SQRT_D 0.17677669529663688f   // 1/sqrt(32)
#define NREP 8                            // accumulator replicas

// ws layout:
//   float idx [4096..4103]  qb[h] = (q_h . bk_h)/sqrt(D)
//   float idx [4104..4111]  ub[h] = u_h . bv_h
//   float idx [4112]        c = w_lin . b_out + b_lin
//   byte 36864..45055       Wb bf16[16][256]: rows 0..7 = (q_h^T Wk_h)/sqrt(D), 8..15 = u_h^T Wv_h
//   byte 65536..            zmf[NREP][G][16] f32: slot 2h = Z, 2h+1 = M
#define WS_QB   4096
#define WS_UB   4104
#define WS_C    4112
#define WB_BYTE_OFF 36864
#define ZM_BYTE_OFF 65536

typedef __attribute__((ext_vector_type(8))) short short8;
typedef __attribute__((ext_vector_type(4))) float f32x4;

__device__ __forceinline__ unsigned short f2bf(float f) {
  unsigned u = __float_as_uint(f);
  unsigned r = (u + 0x7fffu + ((u >> 16) & 1u)) >> 16;   // RNE truncate to bf16
  return (unsigned short)r;
}

__device__ __forceinline__ unsigned int cvt_pk_bf16(float a, float b) {
  __hip_bfloat162 t = __float22bfloat162_rn(float2{a, b});  // v_cvt_pk_bf16_f32
  unsigned int u;
  __builtin_memcpy(&u, &t, 4);
  return u;
}

// ---------------- prep (single kernel, 33 blocks) ---------------------------
// b 0..7  : head-b score fold. Recompute q-slice qh[32] in-block (32 KB of
//           w_in, L2-resident), then wb row b = (q_h^T Wk_h)/sqrt(D), qb[b].
// b 8..15 : value fold j=b-8. Recompute u-slice uh[32] in-block (32 KB of
//           w_out), then wb row 8+j = u_h^T Wv_h, ub[j].
// b 16    : c = w_lin . b_out + b_lin.
// b 17..32: zero zmf.
__global__ __launch_bounds__(256) void prep(
    const float* __restrict__ query, const float* __restrict__ w_in,
    const float* __restrict__ b_in, const float* __restrict__ w_out,
    const float* __restrict__ b_out, const float* __restrict__ b_lin,
    const float* __restrict__ w_lin, float* __restrict__ ws,
    unsigned short* __restrict__ wb, unsigned long long* __restrict__ zm,
    int nzm) {                                       // nzm in u64 units
  const int b = blockIdx.x, t = threadIdx.x;
  if (b < 8) {
    __shared__ float qh[32];
    // phase A: qh[rl] = query . w_in[b*32+rl, :] + b_in  (8 subs x 32 feats)
    {
      const int rl = t >> 3, sub = t & 7;
      const float4* wr = (const float4*)(w_in + (size_t)(b * 32 + rl) * EDIM + sub * 32);
      const float4* qr = (const float4*)(query + sub * 32);
      float p = 0.f;
#pragma unroll
      for (int f4 = 0; f4 < 8; ++f4) {
        const float4 w = wr[f4], q = qr[f4];
        p += w.x * q.x + w.y * q.y + w.z * q.z + w.w * q.w;
      }
      p += __shfl_xor(p, 1, 64);
      p += __shfl_xor(p, 2, 64);
      p += __shfl_xor(p, 4, 64);
      if (sub == 0) qh[rl] = p + b_in[b * 32 + rl];
    }
    __syncthreads();
    // phase B: score-row fold
    float a = 0.f;
#pragma unroll 8
    for (int d = 0; d < 32; ++d)
      a += qh[d] * w_in[(size_t)(EDIM + b * 32 + d) * EDIM + t];
    wb[b * EDIM + t] = f2bf(a * INV_SQRT_D);
    // phase C: qb[b] (wave 0 only)
    if (t < 64) {
      float s = (t < 32) ? qh[t] * b_in[EDIM + b * 32 + t] : 0.f;
#pragma unroll
      for (int m = 32; m >= 1; m >>= 1) s += __shfl_xor(s, m, 64);
      if (t == 0) ws[WS_QB + b] = s * INV_SQRT_D;
    }
  } else if (b < 16) {
    const int j = b - 8;
    __shared__ float uh[32];
    // phase A: uh[dl] = sum_f w_lin[f] * w_out[f][j*32+dl]
    {
      const int dl = t >> 3, sub = t & 7;
      float p = 0.f;
#pragma unroll 8
      for (int f = sub * 32; f < sub * 32 + 32; ++f)
        p += w_lin[f] * w_out[(size_t)f * EDIM + j * 32 + dl];
      p += __shfl_xor(p, 1, 64);
      p += __shfl_xor(p, 2, 64);
      p += __shfl_xor(p, 4, 64);
      if (sub == 0) uh[dl] = p;
    }
    __syncthreads();
    // phase B: value-row fold
    float a = 0.f;
#pragma unroll 8
    for (int d = 0; d < 32; ++d)
      a += uh[d] * w_in[(size_t)(2 * EDIM + j * 32 + d) * EDIM + t];
    wb[(8 + j) * EDIM + t] = f2bf(a);
    // phase C: ub[j] (wave 0 only)
    if (t < 64) {
      float s = (t < 32) ? uh[t] * b_in[2 * EDIM + j * 32 + t] : 0.f;
#pragma unroll
      for (int m = 32; m >= 1; m >>= 1) s += __shfl_xor(s, m, 64);
      if (t == 0) ws[WS_UB + j] = s;
    }
  } else if (b == 16) {
    __shared__ float red[256];
    red[t] = w_lin[t] * b_out[t];
    __syncthreads();
    for (int off = 128; off >= 1; off >>= 1) {
      if (t < off) red[t] += red[t + off];
      __syncthreads();
    }
    if (t == 0) ws[WS_C] = red[0] + b_lin[0];
  } else {
    for (int k = (b - 17) * 256 + t; k < nzm; k += 16 * 256) zm[k] = 0ull;
  }
}

// ---------------- main: direct-fragment MFMA per 16-item tile, no LDS -------
// A-fragment layout for mfma_f32_16x16x32_bf16: lane (n = lane&15, quad =
// lane>>4) holds A[m=n][k=quad*8+j], j=0..7. We load exactly that from x:
// item base+n, feats quad*8 + kc*32 .. +8 (32 B/lane; the wave covers
// 16 items x 128 B contiguous per kc step -> full line utilization).
// Epilogue: f32 atomics into one of NREP replicas (blockIdx&7).
__global__ __launch_bounds__(256, 4) void main_mfma(
    const float* __restrict__ x, const int* __restrict__ gid,
    const float* __restrict__ ws, const unsigned short* __restrict__ wb,
    float* __restrict__ zmf, int g16, int n_items) {
  const int t = threadIdx.x;
  const int lane = t & 63;
  const int n = lane & 15, quad = lane >> 4;
  const int h = n & 7, isw = (n >> 3) & 1;   // n<8: Z (score) slot, n>=8: M slot

  // B fragments: Wb row n (slot), feats quad*8 + kc*32 .. +8
  short8 bfrag[8];
#pragma unroll
  for (int kc = 0; kc < 8; ++kc)
    bfrag[kc] = *(const short8*)(wb + n * EDIM + quad * 8 + kc * 32);

  const float qb = ws[WS_QB + h];
  const float ub = ws[WS_UB + h];

  float* __restrict__ zr = zmf + (size_t)(blockIdx.x & (NREP - 1)) * g16;

  const int wid = (int)(blockIdx.x * (blockDim.x >> 6) + (t >> 6));
  const int nw = (int)(gridDim.x * (blockDim.x >> 6));
  const int ntiles = (n_items + 15) >> 4;

  for (int tile = wid; tile < ntiles; tile += nw) {
    const int base = tile << 4;
    const float* rowp = x + (size_t)(base + n) * EDIM + quad * 8;
    f32x4 acc = {0.f, 0.f, 0.f, 0.f};
    int4 g4;
    if (base + 16 <= n_items) {                    // full tile (hot path)
      g4 = *(const int4*)(gid + base + quad * 4);
#pragma unroll
      for (int kc = 0; kc < 8; ++kc) {
        const float4 v0 = *(const float4*)(rowp + kc * 32);
        const float4 v1 = *(const float4*)(rowp + kc * 32 + 4);
        union { short8 s; unsigned int u[4]; } a;
        a.u[0] = cvt_pk_bf16(v0.x, v0.y);
        a.u[1] = cvt_pk_bf16(v0.z, v0.w);
        a.u[2] = cvt_pk_bf16(v1.x, v1.y);
        a.u[3] = cvt_pk_bf16(v1.z, v1.w);
        acc = __builtin_amdgcn_mfma_f32_16x16x32_bf16(a.s, bfrag[kc], acc, 0, 0, 0);
      }
    } else {                                       // tail tile (unused at N=131072)
      int gg[4];
#pragma unroll
      for (int r = 0; r < 4; ++r)
        gg[r] = (base + quad * 4 + r < n_items) ? gid[base + quad * 4 + r] : 0;
      g4.x = gg[0]; g4.y = gg[1]; g4.z = gg[2]; g4.w = gg[3];
      const bool live = (base + n < n_items);
#pragma unroll
      for (int kc = 0; kc < 8; ++kc) {
        float4 v0 = {0.f, 0.f, 0.f, 0.f}, v1 = {0.f, 0.f, 0.f, 0.f};
        if (live) {
          v0 = *(const float4*)(rowp + kc * 32);
          v1 = *(const float4*)(rowp + kc * 32 + 4);
        }
        union { short8 s; unsigned int u[4]; } a;
        a.u[0] = cvt_pk_bf16(v0.x, v0.y);
        a.u[1] = cvt_pk_bf16(v0.z, v0.w);
        a.u[2] = cvt_pk_bf16(v1.x, v1.y);
        a.u[3] = cvt_pk_bf16(v1.z, v1.w);
        acc = __builtin_amdgcn_mfma_f32_16x16x32_bf16(a.s, bfrag[kc], acc, 0, 0, 0);
      }
    }
    // epilogue: C[m][n] with m = quad*4 + r (item), n = slot
#pragma unroll
    for (int r = 0; r < 4; ++r) {
      const float mine = acc[r];
      const float partner = __shfl_xor(mine, 8, 64);   // slot n^8, same item
      const float sv = (isw ? partner : mine) + qb;
      const float wv = (isw ? mine : partner) + ub;
      const float e = __expf(sv);
      const float val = isw ? e * wv : e;
      const int g = (r == 0) ? g4.x : (r == 1) ? g4.y : (r == 2) ? g4.z : g4.w;
      if (base + quad * 4 + r < n_items)
        atomicAdd(zr + ((size_t)g * 16 + h * 2 + isw), val);
    }
  }
}

// ---------------- finalize: out[g] = c + sum_h M/Z over NREP replicas -------
__global__ __launch_bounds__(256) void finalize(
    const float* __restrict__ zmf, const float* __restrict__ ws,
    float* __restrict__ out, int G) {
  const int g = blockIdx.x * blockDim.x + threadIdx.x;
  if (g >= G) return;
  float zs[8], ms[8];
#pragma unroll
  for (int hh = 0; hh < 8; ++hh) { zs[hh] = 0.f; ms[hh] = 0.f; }
  const int g16 = G * 16;
#pragma unroll
  for (int rep = 0; rep < NREP; ++rep) {
    const float* row = zmf + (size_t)rep * g16 + (size_t)g * 16;
#pragma unroll
    for (int hh = 0; hh < 8; ++hh) {
      zs[hh] += row[hh * 2];
      ms[hh] += row[hh * 2 + 1];
    }
  }
  double acc = (double)ws[WS_C];
#pragma unroll
  for (int hh = 0; hh < 8; ++hh)
    acc += (double)ms[hh] / (double)zs[hh];
  out[g] = (float)acc;
}

// ---------------- Plan B (ws too small): one block per group, no scratch ----
__device__ __forceinline__ float dot16_reduce(const float4 (&W)[16],
                                              const float4 xv, const int lane) {
  float p[16];
#pragma unroll
  for (int j = 0; j < 16; ++j)
    p[j] = W[j].x * xv.x + W[j].y * xv.y + W[j].z * xv.z + W[j].w * xv.w;
#pragma unroll
  for (int j = 0; j < 8; ++j) {
    float send = (lane & 1) ? p[j] : p[j + 8];
    float keep = (lane & 1) ? p[j + 8] : p[j];
    p[j] = keep + __shfl_xor(send, 1, 64);
  }
#pragma unroll
  for (int j = 0; j < 4; ++j) {
    float send = (lane & 2) ? p[j] : p[j + 4];
    float keep = (lane & 2) ? p[j + 4] : p[j];
    p[j] = keep + __shfl_xor(send, 2, 64);
  }
#pragma unroll
  for (int j = 0; j < 2; ++j) {
    float send = (lane & 4) ? p[j] : p[j + 2];
    float keep = (lane & 4) ? p[j + 2] : p[j];
    p[j] = keep + __shfl_xor(send, 4, 64);
  }
  {
    float send = (lane & 8) ? p[0] : p[1];
    float keep = (lane & 8) ? p[1] : p[0];
    p[0] = keep + __shfl_xor(send, 8, 64);
  }
  p[0] += __shfl_xor(p[0], 16, 64);
  p[0] += __shfl_xor(p[0], 32, 64);
  return p[0];
}

__device__ __forceinline__ int bitrev4(const int l4) {
  return ((l4 & 1) << 3) | ((l4 & 2) << 1) | ((l4 & 4) >> 1) | ((l4 & 8) >> 3);
}

__global__ __launch_bounds__(256) void group_scan(
    const float* __restrict__ x, const int* __restrict__ gid,
    const float* __restrict__ query, const float* __restrict__ w_in,
    const float* __restrict__ b_in, const float* __restrict__ w_out,
    const float* __restrict__ b_out, const float* __restrict__ w_lin,
    const float* __restrict__ b_lin, float* __restrict__ out, int n_items) {
  const int g = blockIdx.x;
  const int t = threadIdx.x;
  __shared__ float Wl[16 * EDIM];
  __shared__ float querys[EDIM], wls[EDIM], qs[EDIM], us[EDIM];
  __shared__ float qbias[8], ubias[8], csh;
  __shared__ float part[4][16], sums[16];

  querys[t] = query[t];
  wls[t] = w_lin[t];
  __syncthreads();
  {
    float acc = 0.f;
    const float4* wr = (const float4*)(w_in + (size_t)t * EDIM);
    for (int f4 = 0; f4 < EDIM / 4; ++f4) {
      float4 wv = wr[f4];
      int f = f4 * 4;
      acc += wv.x * querys[f] + wv.y * querys[f + 1] + wv.z * querys[f + 2] + wv.w * querys[f + 3];
    }
    qs[t] = acc + b_in[t];
  }
  {
    float acc = 0.f;
    for (int f = 0; f < EDIM; ++f) acc += wls[f] * w_out[(size_t)f * EDIM + t];
    us[t] = acc;
  }
  __syncthreads();
  for (int j = 0; j < 8; ++j) {
    float a = 0.f;
    for (int d = 0; d < 32; ++d)
      a += qs[j * 32 + d] * w_in[(size_t)(EDIM + j * 32 + d) * EDIM + t];
    Wl[j * EDIM + t] = a * INV_SQRT_D;
  }
  for (int j = 0; j < 8; ++j) {
    float a = 0.f;
    for (int d = 0; d < 32; ++d)
      a += us[j * 32 + d] * w_in[(size_t)(2 * EDIM + j * 32 + d) * EDIM + t];
    Wl[(8 + j) * EDIM + t] = a;
  }
  if (t < 8) {
    float qb = 0.f, ub = 0.f;
    for (int d = 0; d < 32; ++d) {
      qb += qs[t * 32 + d] * b_in[EDIM + t * 32 + d];
      ub += us[t * 32 + d] * b_in[2 * EDIM + t * 32 + d];
    }
    qbias[t] = qb * INV_SQRT_D;
    ubias[t] = ub;
  }
  if (t == 0) {
    float c = b_lin[0];
    for (int f = 0; f < EDIM; ++f) c += wls[f] * b_out[f];
    csh = c;
  }
  __syncthreads();

  const int lane = t & 63;
  const int wave = t >> 6;
  float4 W[16];
#pragma unroll
  for (int j = 0; j < 16; ++j)
    W[j] = *(const float4*)(Wl + j * EDIM + lane * 4);
  const int jv = bitrev4(lane & 15);
  const int h = jv & 7;
  const int isw = (jv >> 3) & 1;
  const float bias_s = qbias[h];
  const float bias_w = ubias[h];

  float accv = 0.f;
  const int nchunk = (n_items + 63) >> 6;
  for (int c = wave; c < nchunk; c += 4) {
    const int i0 = c << 6;
    const int ii = i0 + lane;
    const int gi = (ii < n_items) ? gid[ii] : -1;
    unsigned long long mk = __ballot(gi == g);
    while (mk) {
      const int bpos = __ffsll(mk) - 1;
      mk &= mk - 1;
      const int i = i0 + bpos;
      const float4 xv = *(const float4*)(x + (size_t)i * EDIM + lane * 4);
      const float p0 = dot16_reduce(W, xv, lane);
      const float tpair = __shfl_xor(p0, 1, 64);
      const float sv = (isw ? tpair : p0) + bias_s;
      const float wv = (isw ? p0 : tpair) + bias_w;
      const float e = __expf(sv);
      accv += isw ? e * wv : e;
    }
  }
  if (lane < 16) part[wave][h * 2 + isw] = accv;
  __syncthreads();
  if (t < 16) sums[t] = part[0][t] + part[1][t] + part[2][t] + part[3][t];
  __syncthreads();
  if (t == 0) {
    double acc = (double)csh;
    for (int hh = 0; hh < 8; ++hh)
      acc += (double)sums[2 * hh + 1] / (double)sums[2 * hh];
    out[g] = (float)acc;
  }
}

extern "C" void kernel_launch(void* const* d_in, const int* in_sizes, int n_in,
                              void* d_out, int out_size, void* d_ws, size_t ws_size,
                              hipStream_t stream) {
  const float* tree_preds = (const float*)d_in[0];
  const int* group_ids = (const int*)d_in[1];
  const float* query = (const float*)d_in[2];
  const float* w_in = (const float*)d_in[3];
  const float* b_in = (const float*)d_in[4];
  const float* w_out = (const float*)d_in[5];
  const float* b_out = (const float*)d_in[6];
  const float* w_lin = (const float*)d_in[7];
  const float* b_lin = (const float*)d_in[8];
  float* out = (float*)d_out;

  const int N = in_sizes[1];   // 131072
  const int G = out_size;      // 2048

  const size_t needA = (size_t)ZM_BYTE_OFF + (size_t)NREP * G * 16 * 4;
  if (ws_size >= needA) {
    float* ws = (float*)d_ws;
    unsigned short* wb = (unsigned short*)((char*)d_ws + WB_BYTE_OFF);
    float* zmf = (float*)((char*)d_ws + ZM_BYTE_OFF);
    // zero count in u64 units: NREP*G*16 floats / 2
    prep<<<33, 256, 0, stream>>>(query, w_in, b_in, w_out, b_out, b_lin, w_lin,
                                 ws, wb, (unsigned long long*)zmf, NREP * G * 8);
    main_mfma<<<1024, 256, 0, stream>>>(tree_preds, group_ids, ws, wb, zmf,
                                        G * 16, N);
    finalize<<<(G + 255) / 256, 256, 0, stream>>>(zmf, ws, out, G);
  } else {
    group_scan<<<G, 256, 0, stream>>>(tree_preds, group_ids, query, w_in, b_in,
                                      w_out, b_out, w_lin, b_lin, out, N);
  }
}